// Round 7
// baseline (391.889 us; speedup 1.0000x reference)
//
#include <hip/hip_runtime.h>

#define DD    64      // D
#define TWOD  128     // 2*D
#define RD    256     // RANK*D
#define NT    3       // 16-row subtiles per wave (48 rows)

typedef __attribute__((ext_vector_type(8))) short short8;   // 8 bf16 (MFMA A/B frag)
typedef __attribute__((ext_vector_type(4))) float float4v;  // MFMA C/D frag
typedef __attribute__((ext_vector_type(4))) unsigned uint4v;
typedef unsigned long long ull;
typedef unsigned short ush;

__device__ __forceinline__ ush f2b(float f) {
    unsigned u = __builtin_bit_cast(unsigned, f);
    u += 0x7fffu + ((u >> 16) & 1u);
    return (ush)(u >> 16);
}
__device__ __forceinline__ float b2f(ush s) {
    unsigned u = ((unsigned)s) << 16;
    return __builtin_bit_cast(float, u);
}
// packed f32->bf16 RNE: one VALU op for two converts (identical rounding to f2b)
__device__ __forceinline__ unsigned cvt_pk_bf16(float lo, float hi) {
    unsigned r;
    asm("v_cvt_pk_bf16_f32 %0, %1, %2" : "=v"(r) : "v"(lo), "v"(hi));
    return r;
}
// two bf16 stores at unrelated addresses from one packed convert (2 VALU vs 8)
__device__ __forceinline__ void store_pair(ush* p0, ush* p1, float lo, float hi) {
    unsigned pk = cvt_pk_bf16(lo, hi);
    *p0 = (ush)pk;
    *p1 = (ush)(pk >> 16);
}
// tanh via 1 - 2*rcp(1+exp2(k*x)): 3 VALU + 2 trans (exp, rcp)
__device__ __forceinline__ float ftanh(float x) {
    float e, r;
    asm("v_exp_f32 %0, %1" : "=v"(e) : "v"(x * 2.885390082f));   // exp2(2*log2e*x)
    asm("v_rcp_f32 %0, %1" : "=v"(r) : "v"(e + 1.0f));
    return __builtin_fmaf(-2.0f, r, 1.0f);
}
// Single-wave workgroup: DS ops execute in order per wave, so lgkmcnt(0) +
// a compiler memory fence replaces __syncthreads() (no vmcnt(0) drain ->
// global prefetches stay in flight across stage boundaries).
__device__ __forceinline__ void lds_fence() {
    asm volatile("s_waitcnt lgkmcnt(0)" ::: "memory");
}

// ---------------------------------------------------------------------------
// Prep: bf16 weight layouts so MFMA B-frags are contiguous 16B reads.
// ---------------------------------------------------------------------------
__global__ void prep_weights(const float* __restrict__ W1, const float* __restrict__ W2,
                             ush* __restrict__ wa, ush* __restrict__ wd,
                             ush* __restrict__ wb, ush* __restrict__ wc) {
    int t = blockIdx.x * blockDim.x + threadIdx.x;
    if (t < 8192) {
        wa[t] = f2b(W1[t]);
        int c = t >> 7, r = t & 127;
        wd[t] = f2b(W1[r * 64 + c]);
    }
    if (t < 32768) {
        wb[t] = f2b(W2[t]);
        int c = t >> 8, k = t & 255;
        wc[t] = f2b(W2[k * 128 + c]);
    }
}

// ---------------------------------------------------------------------------
// R4 structure (NT=3, independent 64-thread waves, 5 blocks/CU) with the
// phase loops ROLLED (#pragma unroll 1, 2-step bodies for static A/B
// double-buffer names). Rationale: R4's unrolled body was ~55 KB >> 32 KB
// L1I; waves at different positions thrash instruction fetch — the
// occupancy-insensitive stall seen in R2-R5. Rolled body ~14 KB fits L1I.
// g1p eliminated: (1-h^2) is applied in GEMM4's A-frag build from the still-
// register-resident ha frags (same layout), so GEMM3 stores raw dh.
// ---------------------------------------------------------------------------
__global__ __launch_bounds__(64, 1) void geognn_kernel(
    const float* __restrict__ inp, const float* __restrict__ b1, const float* __restrict__ b2,
    const ush* __restrict__ wa, const ush* __restrict__ wd,
    const ush* __restrict__ wb, const ush* __restrict__ wc,
    float* __restrict__ out, long nrows) {

    // per subtile: phase A (GEMM1->2, 3->4) stride 136 (4352 B);
    //              phase B (GEMM2->mid->3)  stride 264 (8448 B). Time-aliased.
    __shared__ __align__(16) ush hd_s[NT][16 * 264];   // 25344 B
    __shared__ ush v_s[NT][16][68];                    // 6528 B (bf16)
    __shared__ float4v y_s[NT][16];                    // 768 B

    const int  l   = threadIdx.x;
    const int  l15 = l & 15;
    const int  q   = l >> 4;
    long row0 = (long)blockIdx.x * (16 * NT);
    if (row0 + 16 * NT > nrows) row0 = nrows - 16 * NT;   // tail overlap (idempotent)

    // ---- V tiles -> LDS as bf16 (pair-converted), rolled ----
#pragma unroll 1
    for (int r = 0; r < 16; r += 2) {
#pragma unroll
        for (int t = 0; t < NT; ++t) {
            float v0 = inp[(row0 + t * 16 + r)     * TWOD + DD + l];
            float v1 = inp[(row0 + t * 16 + r + 1) * TWOD + DD + l];
            store_pair(&v_s[t][r][l], &v_s[t][r + 1][l], v0, v1);
        }
    }

    // ---- x A-frags, all subtiles: A[m=l15][k=kb*32+q*8+j] ----
    short8 ax[NT][2];
#pragma unroll
    for (int t = 0; t < NT; ++t)
#pragma unroll
        for (int kb = 0; kb < 2; ++kb) {
            const float4v* p = (const float4v*)(inp + (row0 + t * 16 + l15) * TWOD + kb * 32 + q * 8);
            float4v f0 = p[0], f1 = p[1];
            uint4v pk = { cvt_pk_bf16(f0.x, f0.y), cvt_pk_bf16(f0.z, f0.w),
                          cvt_pk_bf16(f1.x, f1.y), cvt_pk_bf16(f1.z, f1.w) };
            ax[t][kb] = __builtin_bit_cast(short8, pk);
        }

    // ---- GEMM1: h = tanh(x @ W1^T + b1)  (48x64x128), rolled over nb ----
    short8 awA[2], awB[2];
#pragma unroll
    for (int f = 0; f < 2; ++f)
        awA[f] = *(const short8*)(wa + (0 * 16 + l15) * DD + f * 32 + q * 8);

    auto g1step = [&](int nb, short8* cur, short8* nxt) {
        if (nb < 7) {
#pragma unroll
            for (int f = 0; f < 2; ++f)
                nxt[f] = *(const short8*)(wa + ((nb + 1) * 16 + l15) * DD + f * 32 + q * 8);
        }
        float bv = b1[nb * 16 + l15];          // 512-B table, L1-resident
        const int c = nb * 16 + l15;
#pragma unroll
        for (int t = 0; t < NT; ++t) {
            float4v acc = {0.f, 0.f, 0.f, 0.f};
            acc = __builtin_amdgcn_mfma_f32_16x16x32_bf16(ax[t][0], cur[0], acc, 0, 0, 0);
            acc = __builtin_amdgcn_mfma_f32_16x16x32_bf16(ax[t][1], cur[1], acc, 0, 0, 0);
            float h0 = ftanh(acc[0] + bv);
            float h1 = ftanh(acc[1] + bv);
            float h2 = ftanh(acc[2] + bv);
            float h3 = ftanh(acc[3] + bv);
            store_pair(&hd_s[t][(q * 4 + 0) * 136 + c], &hd_s[t][(q * 4 + 1) * 136 + c], h0, h1);
            store_pair(&hd_s[t][(q * 4 + 2) * 136 + c], &hd_s[t][(q * 4 + 3) * 136 + c], h2, h3);
        }
    };
#pragma unroll 1
    for (int nbb = 0; nbb < 8; nbb += 2) {
        g1step(nbb,     awA, awB);
        g1step(nbb + 1, awB, awA);
    }

    // preload GEMM2 pair-0 B-frags BEFORE the fence (stays in flight across it)
    short8 bwA[8], bwB[8];
#pragma unroll
    for (int f = 0; f < 8; ++f)
        bwA[f] = *(const short8*)(wb + ((f >> 2) * 16 + l15) * TWOD + (f & 3) * 32 + q * 8);

    lds_fence();   // h writes, v_s visible wave-wide

    // ---- GEMM2: u = tanh(h @ W2^T + b2)  (48x128x256), rolled over p ----
    short8 ha[NT][4];   // h in A-layout; stays LIVE until GEMM4 (g1 recompute)
#pragma unroll
    for (int t = 0; t < NT; ++t)
#pragma unroll
        for (int kb = 0; kb < 4; ++kb)
            ha[t][kb] = *(const short8*)(&hd_s[t][l15 * 136 + kb * 32 + q * 8]);

    lds_fence();   // drain ha reads: h alias dies, d alias writes may begin

    float yp[NT][4] = {};
    auto g2step = [&](int p, short8* cur, short8* nxt) {
        if (p < 7) {
#pragma unroll
            for (int f = 0; f < 8; ++f)
                nxt[f] = *(const short8*)(wb + (((p + 1) * 2 + (f >> 2)) * 16 + l15) * TWOD
                                          + (f & 3) * 32 + q * 8);
        }
#pragma unroll
        for (int s = 0; s < 2; ++s) {
            const int nb = p * 2 + s;
            const int n  = nb * 16 + l15;
            const int c4 = nb * 4 + (l15 >> 2);
            float bv = b2[nb * 16 + l15];      // 1-KB table, L1-resident
#pragma unroll
            for (int t = 0; t < NT; ++t) {
                float4v acc = {0.f, 0.f, 0.f, 0.f};
#pragma unroll
                for (int kb = 0; kb < 4; ++kb)
                    acc = __builtin_amdgcn_mfma_f32_16x16x32_bf16(ha[t][kb], cur[s * 4 + kb], acc, 0, 0, 0);
                float u0 = ftanh(acc[0] + bv);
                float u1 = ftanh(acc[1] + bv);
                float u2 = ftanh(acc[2] + bv);
                float u3 = ftanh(acc[3] + bv);
                store_pair(&hd_s[t][(q * 4 + 0) * 264 + n], &hd_s[t][(q * 4 + 1) * 264 + n], u0, u1);
                store_pair(&hd_s[t][(q * 4 + 2) * 264 + n], &hd_s[t][(q * 4 + 3) * 264 + n], u2, u3);
                yp[t][0] += b2f(v_s[t][q * 4 + 0][c4]) * u0;
                yp[t][1] += b2f(v_s[t][q * 4 + 1][c4]) * u1;
                yp[t][2] += b2f(v_s[t][q * 4 + 2][c4]) * u2;
                yp[t][3] += b2f(v_s[t][q * 4 + 3][c4]) * u3;
            }
        }
    };
#pragma unroll 1
    for (int pp = 0; pp < 8; pp += 2) {
        g2step(pp,     bwA, bwB);
        g2step(pp + 1, bwB, bwA);
    }

    // complete y (each j=l15&3 summed over the 4 lanes sharing it within the quad-row group)
#pragma unroll
    for (int t = 0; t < NT; ++t)
#pragma unroll
        for (int i = 0; i < 4; ++i) {
            yp[t][i] += __shfl_xor(yp[t][i], 4, 64);
            yp[t][i] += __shfl_xor(yp[t][i], 8, 64);
        }
    if (l15 < 4) {
#pragma unroll
        for (int t = 0; t < NT; ++t)
#pragma unroll
            for (int i = 0; i < 4; ++i)
                ((float*)&y_s[t][q * 4 + i])[l15] = yp[t][i];
    }

    // preload GEMM3 nb=0 B-frags before the fence
    short8 cwA[8], cwB[8];
#pragma unroll
    for (int kb = 0; kb < 8; ++kb)
        cwA[kb] = *(const short8*)(wc + l15 * RD + kb * 32 + q * 8);

    lds_fence();   // u (d alias), y_s visible

    // ---- fused mid-pass (rolled): per row, lane l owns cells n=4l..4l+3 ----
#pragma unroll 1
    for (int r = 0; r < 16; ++r) {
#pragma unroll
        for (int t = 0; t < NT; ++t) {
            ull uu = *(const ull*)(&hd_s[t][r * 264 + 4 * l]);
            float4v y = y_s[t][r];
            float vv = b2f(v_s[t][r][l]);
            float u0 = b2f((ush)uu);
            float u1 = b2f((ush)(uu >> 16));
            float u2 = b2f((ush)(uu >> 32));
            float u3 = b2f((ush)(uu >> 48));
            float dvv = y.x * u0 + y.y * u1 + y.z * u2 + y.w * u3;
            out[(row0 + t * 16 + r) * TWOD + DD + l] = -2.0f * dvv;
            float t0 = 2.0f * y.x * vv * (1.0f - u0 * u0);
            float t1 = 2.0f * y.y * vv * (1.0f - u1 * u1);
            float t2 = 2.0f * y.z * vv * (1.0f - u2 * u2);
            float t3 = 2.0f * y.w * vv * (1.0f - u3 * u3);
            unsigned w0 = cvt_pk_bf16(t0, t1);
            unsigned w1 = cvt_pk_bf16(t2, t3);
            ull w = (ull)w0 | ((ull)w1 << 32);
            *(ull*)(&hd_s[t][r * 264 + 4 * l]) = w;
        }
    }

    lds_fence();   // da2 visible

    // ---- GEMM3: dh = da2 @ W2  (48x256x128), rolled; stores RAW dh ----
    short8 da[NT][8];
#pragma unroll
    for (int t = 0; t < NT; ++t)
#pragma unroll
        for (int kb = 0; kb < 8; ++kb)
            da[t][kb] = *(const short8*)(&hd_s[t][l15 * 264 + kb * 32 + q * 8]);

    lds_fence();   // drain da reads: d alias dies, h alias (dh) writes may begin

    auto g3step = [&](int nb, short8* cur, short8* nxt) {
        if (nb < 7) {
#pragma unroll
            for (int kb = 0; kb < 8; ++kb)
                nxt[kb] = *(const short8*)(wc + ((nb + 1) * 16 + l15) * RD + kb * 32 + q * 8);
        }
        const int c = nb * 16 + l15;
#pragma unroll
        for (int t = 0; t < NT; ++t) {
            float4v acc = {0.f, 0.f, 0.f, 0.f};
#pragma unroll
            for (int kb = 0; kb < 8; ++kb)
                acc = __builtin_amdgcn_mfma_f32_16x16x32_bf16(da[t][kb], cur[kb], acc, 0, 0, 0);
            store_pair(&hd_s[t][(q * 4 + 0) * 136 + c], &hd_s[t][(q * 4 + 1) * 136 + c], acc[0], acc[1]);
            store_pair(&hd_s[t][(q * 4 + 2) * 136 + c], &hd_s[t][(q * 4 + 3) * 136 + c], acc[2], acc[3]);
        }
    };
#pragma unroll 1
    for (int nbb = 0; nbb < 8; nbb += 2) {
        g3step(nbb,     cwA, cwB);
        g3step(nbb + 1, cwB, cwA);
    }

    lds_fence();   // raw dh visible

    // ---- GEMM4: dx = (dh * (1-h^2)) @ W1  (48x128x64) -> out[:, :64] ----
    short8 dw[16];
#pragma unroll
    for (int f = 0; f < 16; ++f)
        dw[f] = *(const short8*)(wd + ((f >> 2) * 16 + l15) * TWOD + (f & 3) * 32 + q * 8);

    short8 dfa[NT][4];
#pragma unroll
    for (int t = 0; t < NT; ++t)
#pragma unroll
        for (int kb = 0; kb < 4; ++kb) {
            short8 raw = *(const short8*)(&hd_s[t][l15 * 136 + kb * 32 + q * 8]);
            // fuse g1: a = dh*(1-h^2) = fma(-(dh*h), h, dh); ha has the SAME
            // A-layout (lane=row l15, k=kb*32+q*8+j), register-local.
            uint4v pk;
#pragma unroll
            for (int j = 0; j < 4; ++j) {
                float h0 = b2f((ush)ha[t][kb][2 * j]);
                float d0 = b2f((ush)raw[2 * j]);
                float h1 = b2f((ush)ha[t][kb][2 * j + 1]);
                float d1 = b2f((ush)raw[2 * j + 1]);
                float a0 = __builtin_fmaf(-(d0 * h0), h0, d0);
                float a1 = __builtin_fmaf(-(d1 * h1), h1, d1);
                pk[j] = cvt_pk_bf16(a0, a1);
            }
            dfa[t][kb] = __builtin_bit_cast(short8, pk);
        }
#pragma unroll
    for (int t = 0; t < NT; ++t)
#pragma unroll
        for (int nb = 0; nb < 4; ++nb) {
            float4v acc = {0.f, 0.f, 0.f, 0.f};
#pragma unroll
            for (int kb = 0; kb < 4; ++kb)
                acc = __builtin_amdgcn_mfma_f32_16x16x32_bf16(dfa[t][kb], dw[nb * 4 + kb], acc, 0, 0, 0);
#pragma unroll
            for (int i = 0; i < 4; ++i)
                out[(row0 + t * 16 + q * 4 + i) * TWOD + nb * 16 + l15] = acc[i];
        }
}

extern "C" void kernel_launch(void* const* d_in, const int* in_sizes, int n_in,
                              void* d_out, int out_size, void* d_ws, size_t ws_size,
                              hipStream_t stream) {
    const float* inp = (const float*)d_in[1];
    const float* W1  = (const float*)d_in[2];
    const float* b1  = (const float*)d_in[3];
    const float* W2  = (const float*)d_in[4];
    const float* b2  = (const float*)d_in[5];

    ush* wa = (ush*)d_ws;
    ush* wd = wa + 8192;
    ush* wb = wd + 8192;
    ush* wc = wb + 32768;

    prep_weights<<<128, 256, 0, stream>>>(W1, W2, wa, wd, wb, wc);

    const long rows = in_sizes[1] / TWOD;
    const int  grid = (int)((rows + 16 * NT - 1) / (16 * NT));
    geognn_kernel<<<grid, 64, 0, stream>>>(inp, b1, b2, wa, wd, wb, wc,
                                           (float*)d_out, rows);
}

// Round 8
// 356.501 us; speedup vs baseline: 1.0993x; 1.0993x over previous
//
#include <hip/hip_runtime.h>

#define DD    64      // D
#define TWOD  128     // 2*D
#define RD    256     // RANK*D
#define NT    3       // 16-row subtiles per wave (48 rows)

typedef __attribute__((ext_vector_type(8))) short short8;   // 8 bf16 (MFMA A/B frag)
typedef __attribute__((ext_vector_type(4))) float float4v;  // MFMA C/D frag
typedef __attribute__((ext_vector_type(4))) unsigned uint4v;
typedef unsigned long long ull;
typedef unsigned short ush;

__device__ __forceinline__ ush f2b(float f) {
    unsigned u = __builtin_bit_cast(unsigned, f);
    u += 0x7fffu + ((u >> 16) & 1u);
    return (ush)(u >> 16);
}
__device__ __forceinline__ float b2f(ush s) {
    unsigned u = ((unsigned)s) << 16;
    return __builtin_bit_cast(float, u);
}
// packed f32->bf16 RNE: one VALU op for two converts (identical rounding to f2b)
__device__ __forceinline__ unsigned cvt_pk_bf16(float lo, float hi) {
    unsigned r;
    asm("v_cvt_pk_bf16_f32 %0, %1, %2" : "=v"(r) : "v"(lo), "v"(hi));
    return r;
}
// two bf16 stores at unrelated addresses from one packed convert (2 VALU vs 8)
__device__ __forceinline__ void store_pair(ush* p0, ush* p1, float lo, float hi) {
    unsigned pk = cvt_pk_bf16(lo, hi);
    *p0 = (ush)pk;
    *p1 = (ush)(pk >> 16);
}
// tanh via 1 - 2*rcp(1+exp2(k*x)): 3 VALU + 2 trans (exp, rcp)
__device__ __forceinline__ float ftanh(float x) {
    float e, r;
    asm("v_exp_f32 %0, %1" : "=v"(e) : "v"(x * 2.885390082f));   // exp2(2*log2e*x)
    asm("v_rcp_f32 %0, %1" : "=v"(r) : "v"(e + 1.0f));
    return __builtin_fmaf(-2.0f, r, 1.0f);
}
// Single-wave workgroup: DS ops execute in order per wave, so lgkmcnt(0) +
// a compiler memory fence replaces __syncthreads() (no vmcnt(0) drain ->
// global prefetches stay in flight across stage boundaries).
__device__ __forceinline__ void lds_fence() {
    asm volatile("s_waitcnt lgkmcnt(0)" ::: "memory");
}

// ---------------------------------------------------------------------------
// Prep: bf16 weight layouts so MFMA B-frags are contiguous 16B reads.
// ---------------------------------------------------------------------------
__global__ void prep_weights(const float* __restrict__ W1, const float* __restrict__ W2,
                             ush* __restrict__ wa, ush* __restrict__ wd,
                             ush* __restrict__ wb, ush* __restrict__ wc) {
    int t = blockIdx.x * blockDim.x + threadIdx.x;
    if (t < 8192) {
        wa[t] = f2b(W1[t]);
        int c = t >> 7, r = t & 127;
        wd[t] = f2b(W1[r * 64 + c]);
    }
    if (t < 32768) {
        wb[t] = f2b(W2[t]);
        int c = t >> 8, k = t & 255;
        wc[t] = f2b(W2[k * 128 + c]);
    }
}

// ---------------------------------------------------------------------------
// R4 structure (NT=3 unrolled, independent 64-thread waves) + DEPTH-2 weight
// prefetch. R7 showed the stall is exposed weight-load latency (rolled loops
// degraded the compiler's cross-step pipeline -> +22%). Changes vs R4:
//  * h_s/d_s DE-ALIASED (separate buffers, LDS 45.7 KB -> 3 blocks/CU; R2-R4
//    proved occupancy 10-30% is perf-neutral). h survives to GEMM4, so g1p
//    registers (48 VGPR) are gone: GEMM3 stores raw dh; GEMM4 rebuilds
//    da1 = dh*(1-h^2) from LDS. 2 fewer fences.
//  * GEMM2/GEMM3: explicit 3-buffer depth-2 prefetch, prologue batches
//    issued BEFORE the preceding fence (in flight across the whole prior
//    phase). launch_bounds(64,1): at 3 waves/CU the VGPR cap is irrelevant.
// ---------------------------------------------------------------------------
__global__ __launch_bounds__(64, 1) void geognn_kernel(
    const float* __restrict__ inp, const float* __restrict__ b1, const float* __restrict__ b2,
    const ush* __restrict__ wa, const ush* __restrict__ wd,
    const ush* __restrict__ wb, const ush* __restrict__ wc,
    float* __restrict__ out, long nrows) {

    __shared__ __align__(16) ush h_s[NT][16 * 136];   // h (GEMM1->2, re-read in GEMM4)
    __shared__ __align__(16) ush d_s[NT][16 * 264];   // u -> da2 -> raw dh (stride 136)
    __shared__ ush v_s[NT][16][68];                   // v bf16
    __shared__ float4v y_s[NT][16];

    const int  l   = threadIdx.x;
    const int  l15 = l & 15;
    const int  q   = l >> 4;
    long row0 = (long)blockIdx.x * (16 * NT);
    if (row0 + 16 * NT > nrows) row0 = nrows - 16 * NT;   // tail overlap (idempotent)

    // ---- V tiles -> LDS as bf16 (pair-converted) ----
#pragma unroll
    for (int t = 0; t < NT; ++t)
#pragma unroll
        for (int r = 0; r < 16; r += 2) {
            float v0 = inp[(row0 + t * 16 + r)     * TWOD + DD + l];
            float v1 = inp[(row0 + t * 16 + r + 1) * TWOD + DD + l];
            store_pair(&v_s[t][r][l], &v_s[t][r + 1][l], v0, v1);
        }

    // ---- x A-frags, all subtiles: A[m=l15][k=kb*32+q*8+j] ----
    short8 ax[NT][2];
#pragma unroll
    for (int t = 0; t < NT; ++t)
#pragma unroll
        for (int kb = 0; kb < 2; ++kb) {
            const float4v* p = (const float4v*)(inp + (row0 + t * 16 + l15) * TWOD + kb * 32 + q * 8);
            float4v f0 = p[0], f1 = p[1];
            uint4v pk = { cvt_pk_bf16(f0.x, f0.y), cvt_pk_bf16(f0.z, f0.w),
                          cvt_pk_bf16(f1.x, f1.y), cvt_pk_bf16(f1.z, f1.w) };
            ax[t][kb] = __builtin_bit_cast(short8, pk);
        }

    // ---- GEMM1: h = tanh(x @ W1^T + b1)  (48x64x128); all 16 B-frags preloaded ----
    short8 aw[16];
#pragma unroll
    for (int f = 0; f < 16; ++f)
        aw[f] = *(const short8*)(wa + ((f >> 1) * 16 + l15) * DD + (f & 1) * 32 + q * 8);

#pragma unroll
    for (int nb = 0; nb < 8; ++nb) {
        float bv = b1[nb * 16 + l15];
        const int c = nb * 16 + l15;
#pragma unroll
        for (int t = 0; t < NT; ++t) {
            float4v acc = {0.f, 0.f, 0.f, 0.f};
            acc = __builtin_amdgcn_mfma_f32_16x16x32_bf16(ax[t][0], aw[nb * 2 + 0], acc, 0, 0, 0);
            acc = __builtin_amdgcn_mfma_f32_16x16x32_bf16(ax[t][1], aw[nb * 2 + 1], acc, 0, 0, 0);
            float h0 = ftanh(acc[0] + bv);
            float h1 = ftanh(acc[1] + bv);
            float h2 = ftanh(acc[2] + bv);
            float h3 = ftanh(acc[3] + bv);
            store_pair(&h_s[t][(q * 4 + 0) * 136 + c], &h_s[t][(q * 4 + 1) * 136 + c], h0, h1);
            store_pair(&h_s[t][(q * 4 + 2) * 136 + c], &h_s[t][(q * 4 + 3) * 136 + c], h2, h3);
        }
    }

    // ---- GEMM2 prologue: weight batches 0,1 in flight across the fence ----
    short8 bw0[8], bw1[8], bw2[8];
#define WB_LOAD(buf, b)                                                              \
    _Pragma("unroll")                                                                \
    for (int f = 0; f < 8; ++f)                                                      \
        buf[f] = *(const short8*)(wb + (((b) * 2 + (f >> 2)) * 16 + l15) * TWOD      \
                                  + (f & 3) * 32 + q * 8);
    WB_LOAD(bw0, 0)
    WB_LOAD(bw1, 1)

    lds_fence();   // F1: h, v visible wave-wide

    // ---- GEMM2: u = tanh(h @ W2^T + b2)  (48x128x256), fused y partials ----
    short8 ha[NT][4];
#pragma unroll
    for (int t = 0; t < NT; ++t)
#pragma unroll
        for (int kb = 0; kb < 4; ++kb)
            ha[t][kb] = *(const short8*)(&h_s[t][l15 * 136 + kb * 32 + q * 8]);

    float yp[NT][4] = {};
    auto g2step = [&](int p, short8* cur, short8* nxt) {
        if (nxt) { WB_LOAD(nxt, p + 2) }      // depth-2: batch p+2 issued at step p
#pragma unroll
        for (int s = 0; s < 2; ++s) {
            const int nb = p * 2 + s;
            const int n  = nb * 16 + l15;
            const int c4 = nb * 4 + (l15 >> 2);
            float bv = b2[nb * 16 + l15];
#pragma unroll
            for (int t = 0; t < NT; ++t) {
                float4v acc = {0.f, 0.f, 0.f, 0.f};
#pragma unroll
                for (int kb = 0; kb < 4; ++kb)
                    acc = __builtin_amdgcn_mfma_f32_16x16x32_bf16(ha[t][kb], cur[s * 4 + kb], acc, 0, 0, 0);
                float u0 = ftanh(acc[0] + bv);
                float u1 = ftanh(acc[1] + bv);
                float u2 = ftanh(acc[2] + bv);
                float u3 = ftanh(acc[3] + bv);
                store_pair(&d_s[t][(q * 4 + 0) * 264 + n], &d_s[t][(q * 4 + 1) * 264 + n], u0, u1);
                store_pair(&d_s[t][(q * 4 + 2) * 264 + n], &d_s[t][(q * 4 + 3) * 264 + n], u2, u3);
                yp[t][0] += b2f(v_s[t][q * 4 + 0][c4]) * u0;
                yp[t][1] += b2f(v_s[t][q * 4 + 1][c4]) * u1;
                yp[t][2] += b2f(v_s[t][q * 4 + 2][c4]) * u2;
                yp[t][3] += b2f(v_s[t][q * 4 + 3][c4]) * u3;
            }
        }
    };
    g2step(0, bw0, bw2);
    g2step(1, bw1, bw0);
    g2step(2, bw2, bw1);
    g2step(3, bw0, bw2);
    g2step(4, bw1, bw0);
    g2step(5, bw2, bw1);
    g2step(6, bw0, nullptr);
    g2step(7, bw1, nullptr);

    // complete y (each j=l15&3 summed over the 4 lanes sharing it within the quad-row group)
#pragma unroll
    for (int t = 0; t < NT; ++t)
#pragma unroll
        for (int i = 0; i < 4; ++i) {
            yp[t][i] += __shfl_xor(yp[t][i], 4, 64);
            yp[t][i] += __shfl_xor(yp[t][i], 8, 64);
        }
    if (l15 < 4) {
#pragma unroll
        for (int t = 0; t < NT; ++t)
#pragma unroll
            for (int i = 0; i < 4; ++i)
                ((float*)&y_s[t][q * 4 + i])[l15] = yp[t][i];
    }

    // ---- GEMM3 prologue: batches 0,1 in flight across fence + mid-pass ----
    short8 cw0[8], cw1[8], cw2[8];
#define WC_LOAD(buf, b)                                                              \
    _Pragma("unroll")                                                                \
    for (int kb = 0; kb < 8; ++kb)                                                   \
        buf[kb] = *(const short8*)(wc + ((b) * 16 + l15) * RD + kb * 32 + q * 8);
    WC_LOAD(cw0, 0)
    WC_LOAD(cw1, 1)

    lds_fence();   // F2: u (d_s), y_s visible

    // ---- fused mid-pass: per row, lane l owns cells n=4l..4l+3 of u ----
    //   dv_l = 2*sum_j y_j*u[4l+j]  -> out (coalesced)
    //   da2[4l+j] = 2*y_j*v_l*(1-u^2) -> write back in place (same lane, same addr)
#pragma unroll
    for (int t = 0; t < NT; ++t)
#pragma unroll
        for (int r = 0; r < 16; ++r) {
            ull uu = *(const ull*)(&d_s[t][r * 264 + 4 * l]);
            float4v y = y_s[t][r];
            float vv = b2f(v_s[t][r][l]);
            float u0 = b2f((ush)uu);
            float u1 = b2f((ush)(uu >> 16));
            float u2 = b2f((ush)(uu >> 32));
            float u3 = b2f((ush)(uu >> 48));
            float dvv = y.x * u0 + y.y * u1 + y.z * u2 + y.w * u3;
            out[(row0 + t * 16 + r) * TWOD + DD + l] = -2.0f * dvv;
            float t0 = 2.0f * y.x * vv * (1.0f - u0 * u0);
            float t1 = 2.0f * y.y * vv * (1.0f - u1 * u1);
            float t2 = 2.0f * y.z * vv * (1.0f - u2 * u2);
            float t3 = 2.0f * y.w * vv * (1.0f - u3 * u3);
            unsigned w0 = cvt_pk_bf16(t0, t1);
            unsigned w1 = cvt_pk_bf16(t2, t3);
            ull w = (ull)w0 | ((ull)w1 << 32);
            *(ull*)(&d_s[t][r * 264 + 4 * l]) = w;
        }

    lds_fence();   // F3: da2 visible

    // ---- GEMM3: dh = da2 @ W2  (48x256x128); stores RAW dh (stride 136) ----
    short8 da[NT][8];
#pragma unroll
    for (int t = 0; t < NT; ++t)
#pragma unroll
        for (int kb = 0; kb < 8; ++kb)
            da[t][kb] = *(const short8*)(&d_s[t][l15 * 264 + kb * 32 + q * 8]);

    lds_fence();   // F4: drain da reads; d_s dies, dh writes may begin

    auto g3step = [&](int nb, short8* cur, short8* nxt) {
        if (nxt) { WC_LOAD(nxt, nb + 2) }     // depth-2
        const int c = nb * 16 + l15;
#pragma unroll
        for (int t = 0; t < NT; ++t) {
            float4v acc = {0.f, 0.f, 0.f, 0.f};
#pragma unroll
            for (int kb = 0; kb < 8; ++kb)
                acc = __builtin_amdgcn_mfma_f32_16x16x32_bf16(da[t][kb], cur[kb], acc, 0, 0, 0);
            store_pair(&d_s[t][(q * 4 + 0) * 136 + c], &d_s[t][(q * 4 + 1) * 136 + c], acc[0], acc[1]);
            store_pair(&d_s[t][(q * 4 + 2) * 136 + c], &d_s[t][(q * 4 + 3) * 136 + c], acc[2], acc[3]);
        }
    };
    g3step(0, cw0, cw2);
    g3step(1, cw1, cw0);
    g3step(2, cw2, cw1);
    g3step(3, cw0, cw2);
    g3step(4, cw1, cw0);
    g3step(5, cw2, cw1);
    g3step(6, cw0, nullptr);
    g3step(7, cw1, nullptr);

    // preload all 16 GEMM4 B-frags before the fence
    short8 dw[16];
#pragma unroll
    for (int f = 0; f < 16; ++f)
        dw[f] = *(const short8*)(wd + ((f >> 2) * 16 + l15) * TWOD + (f & 3) * 32 + q * 8);

    lds_fence();   // F5: raw dh visible

    // ---- GEMM4: dx = (dh * (1-h^2)) @ W1  (48x128x64) -> out[:, :64] ----
    // g1 rebuilt from LDS h (h_s intact since GEMM1): a = fma(-(dh*h), h, dh).
    short8 dfa[NT][4];
#pragma unroll
    for (int t = 0; t < NT; ++t)
#pragma unroll
        for (int kb = 0; kb < 4; ++kb) {
            short8 rawd = *(const short8*)(&d_s[t][l15 * 136 + kb * 32 + q * 8]);
            short8 rawh = *(const short8*)(&h_s[t][l15 * 136 + kb * 32 + q * 8]);
            uint4v pk;
#pragma unroll
            for (int j = 0; j < 4; ++j) {
                float d0 = b2f((ush)rawd[2 * j]);
                float h0 = b2f((ush)rawh[2 * j]);
                float d1 = b2f((ush)rawd[2 * j + 1]);
                float h1 = b2f((ush)rawh[2 * j + 1]);
                float a0 = __builtin_fmaf(-(d0 * h0), h0, d0);
                float a1 = __builtin_fmaf(-(d1 * h1), h1, d1);
                pk[j] = cvt_pk_bf16(a0, a1);
            }
            dfa[t][kb] = __builtin_bit_cast(short8, pk);
        }
#pragma unroll
    for (int t = 0; t < NT; ++t)
#pragma unroll
        for (int nb = 0; nb < 4; ++nb) {
            float4v acc = {0.f, 0.f, 0.f, 0.f};
#pragma unroll
            for (int kb = 0; kb < 4; ++kb)
                acc = __builtin_amdgcn_mfma_f32_16x16x32_bf16(dfa[t][kb], dw[nb * 4 + kb], acc, 0, 0, 0);
#pragma unroll
            for (int i = 0; i < 4; ++i)
                out[(row0 + t * 16 + q * 4 + i) * TWOD + nb * 16 + l15] = acc[i];
        }
#undef WB_LOAD
#undef WC_LOAD
}

extern "C" void kernel_launch(void* const* d_in, const int* in_sizes, int n_in,
                              void* d_out, int out_size, void* d_ws, size_t ws_size,
                              hipStream_t stream) {
    const float* inp = (const float*)d_in[1];
    const float* W1  = (const float*)d_in[2];
    const float* b1  = (const float*)d_in[3];
    const float* W2  = (const float*)d_in[4];
    const float* b2  = (const float*)d_in[5];

    ush* wa = (ush*)d_ws;
    ush* wd = wa + 8192;
    ush* wb = wd + 8192;
    ush* wc = wb + 32768;

    prep_weights<<<128, 256, 0, stream>>>(W1, W2, wa, wd, wb, wc);

    const long rows = in_sizes[1] / TWOD;
    const int  grid = (int)((rows + 16 * NT - 1) / (16 * NT));
    geognn_kernel<<<grid, 64, 0, stream>>>(inp, b1, b2, wa, wd, wb, wc,
                                           (float*)d_out, rows);
}